// Round 1
// baseline (4390.836 us; speedup 1.0000x reference)
//
#include <hip/hip_runtime.h>
#include <math.h>

#define NN 262144
#define EE 2097152
#define BB 16
#define SS 7744
#define GG 484
#define NSLOT (SS*484)

__device__ __forceinline__ float eluf(float x){ return x > 0.f ? x : expm1f(x); }

// ---------------- CSR build ----------------
__global__ __launch_bounds__(256) void k_deg(const int* __restrict__ dst, int* __restrict__ deg)
{
  int gid = blockIdx.x*256 + threadIdx.x;
  int stride = gridDim.x*256;
  for (int e = gid; e < EE; e += stride) atomicAdd(&deg[dst[e]], 1);
}

__global__ __launch_bounds__(256) void k_scan1(const int* __restrict__ in, int* __restrict__ out,
                                               int* __restrict__ bsum, int n)
{
  __shared__ int sh[256];
  int t = threadIdx.x, gid = blockIdx.x*256 + t;
  int v = (gid < n) ? in[gid] : 0;
  sh[t] = v; __syncthreads();
  for (int off=1; off<256; off<<=1){
    int tmp = (t >= off) ? sh[t-off] : 0;
    __syncthreads();
    sh[t] += tmp;
    __syncthreads();
  }
  if (gid < n) out[gid] = sh[t] - v;
  if (t == 255) bsum[blockIdx.x] = sh[255];
}

__global__ __launch_bounds__(1024) void k_scan2(int* __restrict__ bsum, int nb)
{
  __shared__ int sh[1024];
  int t = threadIdx.x;
  int v = (t < nb) ? bsum[t] : 0;
  sh[t] = v; __syncthreads();
  for (int off=1; off<1024; off<<=1){
    int tmp = (t >= off) ? sh[t-off] : 0;
    __syncthreads();
    sh[t] += tmp;
    __syncthreads();
  }
  if (t < nb) bsum[t] = sh[t] - v;
  if (t == nb-1) bsum[1024] = sh[t];
}

__global__ __launch_bounds__(256) void k_scan3(int* __restrict__ out, const int* __restrict__ bsum, int n)
{
  int gid = blockIdx.x*256 + threadIdx.x;
  if (gid < n) out[gid] += bsum[blockIdx.x];
  if (gid == 0) out[n] = bsum[1024];
}

__global__ __launch_bounds__(256) void k_scatter(const int* __restrict__ src, const int* __restrict__ dst,
                          const float2* __restrict__ ea, const int* __restrict__ rowstart,
                          int* __restrict__ cursor, int* __restrict__ csr_src, float2* __restrict__ csr_f)
{
  int gid = blockIdx.x*256 + threadIdx.x;
  int stride = gridDim.x*256;
  for (int e = gid; e < EE; e += stride){
    int d = dst[e];
    int p = atomicAdd(&cursor[d], 1);
    int slot = rowstart[d] + p;
    csr_src[slot] = src[e];
    float2 f = ea[e];
    f.x = fminf(fmaxf(f.x, 0.f), 1.f);
    f.y = fminf(fmaxf(f.y, 0.f), 1.f);
    csr_f[slot] = f;
  }
}

// ---------------- node spline conv (z-decomposition) ----------------
// MODE 0: raw input, 1: folded-BN input, 2: residual (two folded-BN inputs summed)
template<int CIN, int COUT, int MODE>
__global__ __launch_bounds__(256) void k_conv(
    const float* __restrict__ xin, const float* __restrict__ xin2,
    const float* __restrict__ scshA, const float* __restrict__ scshB,
    const int* __restrict__ rowstart, const int* __restrict__ csr_src,
    const float2* __restrict__ csr_f, const float* __restrict__ W,
    float* __restrict__ aout)
{
  int d = blockIdx.x*256 + threadIdx.x;
  float sc[CIN], sh[CIN], sc2[CIN], sh2[CIN];
  #pragma unroll
  for (int i=0;i<CIN;i++){
    if (MODE >= 1){ sc[i]=scshA[i]; sh[i]=scshA[32+i]; }
    if (MODE == 2){ sc2[i]=scshB[i]; sh2[i]=scshB[32+i]; }
  }
  float z[4*CIN];
  #pragma unroll
  for (int j=0;j<4*CIN;j++) z[j]=0.f;
  int rs = rowstart[d], re = rowstart[d+1];
  for (int s = rs; s < re; ++s){
    int srcn = csr_src[s];
    float2 f = csr_f[s];
    float b0=(1.f-f.x)*(1.f-f.y), b1=f.x*(1.f-f.y), b2=(1.f-f.x)*f.y, b3=f.x*f.y;
    float xv[CIN];
    if constexpr ((CIN & 3) == 0){
      const float4* xr = reinterpret_cast<const float4*>(xin + (size_t)srcn*CIN);
      #pragma unroll
      for (int q=0;q<CIN/4;q++){ float4 t=xr[q]; xv[4*q]=t.x; xv[4*q+1]=t.y; xv[4*q+2]=t.z; xv[4*q+3]=t.w; }
    } else {
      const float2* xr = reinterpret_cast<const float2*>(xin + (size_t)srcn*CIN);
      #pragma unroll
      for (int q=0;q<CIN/2;q++){ float2 t=xr[q]; xv[2*q]=t.x; xv[2*q+1]=t.y; }
    }
    float xw[(MODE==2) ? CIN : 1];
    if constexpr (MODE == 2){
      const float4* yr = reinterpret_cast<const float4*>(xin2 + (size_t)srcn*CIN);
      #pragma unroll
      for (int q=0;q<CIN/4;q++){ float4 t=yr[q]; xw[4*q]=t.x; xw[4*q+1]=t.y; xw[4*q+2]=t.z; xw[4*q+3]=t.w; }
    }
    #pragma unroll
    for (int i=0;i<CIN;i++){
      float v = xv[i];
      if (MODE == 1) v = fmaf(v, sc[i], sh[i]);
      if (MODE == 2) v = fmaf(v, sc[i], sh[i]) + fmaf(xw[i], sc2[i], sh2[i]);
      z[i]       = fmaf(b0, v, z[i]);
      z[CIN+i]   = fmaf(b1, v, z[CIN+i]);
      z[2*CIN+i] = fmaf(b2, v, z[2*CIN+i]);
      z[3*CIN+i] = fmaf(b3, v, z[3*CIN+i]);
    }
  }
  float out[COUT];
  #pragma unroll
  for (int c=0;c<COUT;c++) out[c]=0.f;
  #pragma unroll
  for (int j=0;j<4*CIN;j++){
    const float* wr = W + j*COUT;
    float zj = z[j];
    #pragma unroll
    for (int c=0;c<COUT;c++) out[c] = fmaf(zj, wr[c], out[c]);
  }
  float invd = 1.f / fmaxf((float)(re - rs), 1.f);
  float4* orow = reinterpret_cast<float4*>(aout + (size_t)d*COUT);
  #pragma unroll
  for (int q=0;q<COUT/4;q++){
    float4 t;
    t.x = eluf(out[4*q+0]*invd);
    t.y = eluf(out[4*q+1]*invd);
    t.z = eluf(out[4*q+2]*invd);
    t.w = eluf(out[4*q+3]*invd);
    orow[q] = t;
  }
}

// ---------------- BN statistics (column-major coalesced) ----------------
template<int C, bool WEIGHTED>
__global__ __launch_bounds__(256) void k_stats(const float* __restrict__ a, const float* __restrict__ wcnt,
                                               float* __restrict__ stats, int n)
{
  int t = blockIdx.x*256 + threadIdx.x;
  int T = gridDim.x*256;
  float s1=0.f, s2=0.f;
  int M = n*C;
  for (int e = t; e < M; e += T){
    float v = a[e];
    if (WEIGHTED){ if (!(wcnt[e/C] > 0.f)) continue; }
    s1 += v; s2 += v*v;
  }
  __shared__ float sh[256];
  int lt = threadIdx.x;
  sh[lt] = s1; __syncthreads();
  #pragma unroll
  for (int off=128; off>=C; off>>=1){ if (lt<off) sh[lt]+=sh[lt+off]; __syncthreads(); }
  if (lt < C) atomicAdd(&stats[lt], sh[lt]);
  __syncthreads();
  sh[lt] = s2; __syncthreads();
  #pragma unroll
  for (int off=128; off>=C; off>>=1){ if (lt<off) sh[lt]+=sh[lt+off]; __syncthreads(); }
  if (lt < C) atomicAdd(&stats[C+lt], sh[lt]);
}

__global__ void k_fin(const float* __restrict__ stats, const float* __restrict__ g,
                      const float* __restrict__ b, float* __restrict__ scsh,
                      const float* __restrict__ twp, float denomN, int C)
{
  int c = threadIdx.x;
  if (c >= C) return;
  float cntv = twp ? *twp : denomN;
  float m = stats[c] / cntv;
  float var = stats[C+c] / cntv - m*m;
  float scl = g[c] * rsqrtf(var + 1e-5f);
  scsh[c] = scl;
  scsh[32+c] = fmaf(-m, scl, b[c]);
}

// ---------------- pooling ----------------
__global__ __launch_bounds__(256) void k_pool1(const float2* __restrict__ pos, const float* __restrict__ a5,
                      const float* __restrict__ scsh5, int* __restrict__ cid,
                      float* __restrict__ cnt, float* __restrict__ ppsum, unsigned* __restrict__ xpkey)
{
  int n = blockIdx.x*256 + threadIdx.x;
  float2 p = pos[n];
  const float SXf = (float)(16.0/346.0);
  const float SYf = (float)(12.0/260.0);
  int cx = (int)floorf(p.x / SXf); cx = min(max(cx, 0), 21);
  int cy = (int)floorf(p.y / SYf); cy = min(max(cy, 0), 21);
  int cd = (n >> 14) * GG + cy*22 + cx;
  cid[n] = cd;
  atomicAdd(&cnt[cd], 1.f);
  atomicAdd(&ppsum[2*cd],   p.x);
  atomicAdd(&ppsum[2*cd+1], p.y);
  const float4* ar = reinterpret_cast<const float4*>(a5 + (size_t)n*32);
  #pragma unroll
  for (int q=0;q<8;q++){
    float4 tv = ar[q];
    float vv[4] = {tv.x, tv.y, tv.z, tv.w};
    #pragma unroll
    for (int j=0;j<4;j++){
      int c = 4*q + j;
      float h = fmaf(vv[j], scsh5[c], scsh5[32+c]);
      unsigned u = __float_as_uint(h);
      unsigned key = (u & 0x80000000u) ? ~u : (u | 0x80000000u);
      atomicMax(&xpkey[cd*32 + c], key);
    }
  }
}

__global__ __launch_bounds__(256) void k_pool2(const float* __restrict__ cnt, const float* __restrict__ ppsum,
                      const unsigned* __restrict__ xpkey, float2* __restrict__ pp,
                      float* __restrict__ xpf, float* __restrict__ tw)
{
  int q = blockIdx.x*256 + threadIdx.x;
  bool act = q < SS;
  float cn = act ? cnt[q] : 0.f;
  bool val = cn > 0.f;
  if (act){
    float inv = 1.f / fmaxf(cn, 1.f);
    pp[q] = make_float2(ppsum[2*q]*inv, ppsum[2*q+1]*inv);
    #pragma unroll
    for (int c=0;c<32;c++){
      float xv = 0.f;
      if (val){
        unsigned key = xpkey[q*32+c];
        unsigned u = (key & 0x80000000u) ? (key ^ 0x80000000u) : ~key;
        xv = __uint_as_float(u);
      }
      xpf[q*32+c] = xv;
    }
  }
  unsigned long long m = __ballot(val);
  if ((threadIdx.x & 63) == 0) atomicAdd(tw, (float)__popcll(m));
}

__global__ __launch_bounds__(256) void k_slot(const int* __restrict__ src, const int* __restrict__ dst,
                      const int* __restrict__ cid, unsigned char* __restrict__ slotb)
{
  int gid = blockIdx.x*256 + threadIdx.x;
  int stride = gridDim.x*256;
  for (int e = gid; e < EE; e += stride){
    int cs = cid[src[e]];
    int cdd = cid[dst[e]];
    if (cs != cdd){
      int g = cs / GG;
      slotb[(size_t)cs*GG + (cdd - g*GG)] = 1;
    }
  }
}

__global__ __launch_bounds__(256) void k_pair_deg(const unsigned char* __restrict__ slotb,
                      const float2* __restrict__ pp, int* __restrict__ deg2, unsigned* __restrict__ mxp)
{
  int gid = blockIdx.x*256 + threadIdx.x;
  int stride = gridDim.x*256;
  float lm = 0.f;
  for (int s = gid; s < NSLOT; s += stride){
    if (slotb[s]){
      int cs = s / GG; int lcd = s - cs*GG;
      int g = cs / GG; int cdd = g*GG + lcd;
      atomicAdd(&deg2[cdd], 1);
      float2 a = pp[cs], b = pp[cdd];
      lm = fmaxf(lm, fmaxf(fabsf(a.x-b.x), fabsf(a.y-b.y)));
    }
  }
  __shared__ float sh[256];
  sh[threadIdx.x] = lm; __syncthreads();
  for (int off=128; off; off>>=1){ if (threadIdx.x<off) sh[threadIdx.x]=fmaxf(sh[threadIdx.x],sh[threadIdx.x+off]); __syncthreads(); }
  if (threadIdx.x==0) atomicMax(mxp, __float_as_uint(sh[0]));
}

__global__ __launch_bounds__(256) void k_pair_fill(const unsigned char* __restrict__ slotb,
                      const int* __restrict__ rowstart2, int* __restrict__ cursor2, int* __restrict__ pairsrc)
{
  int gid = blockIdx.x*256 + threadIdx.x;
  int stride = gridDim.x*256;
  for (int s = gid; s < NSLOT; s += stride){
    if (slotb[s]){
      int cs = s / GG; int lcd = s - cs*GG;
      int g = cs / GG; int cdd = g*GG + lcd;
      int p = atomicAdd(&cursor2[cdd], 1);
      pairsrc[rowstart2[cdd] + p] = cs;
    }
  }
}

// ---------------- pool spline conv: 1 wave per dst cell ----------------
__global__ __launch_bounds__(64) void k_pconv(const float* __restrict__ xin, const float* __restrict__ scsh,
                      const int* __restrict__ rowstart2, const int* __restrict__ pairsrc,
                      const float2* __restrict__ pp, const float* __restrict__ mxp,
                      const float* __restrict__ W, float* __restrict__ aout)
{
  int d = blockIdx.x;
  int l = threadIdx.x;
  int c = l & 31, k0 = l >> 5;
  float denom = 2.f * (*mxp) + 1e-12f;
  float2 ppd = pp[d];
  float scc = 1.f, shc = 0.f;
  if (scsh){ scc = scsh[c]; shc = scsh[32+c]; }
  int rs = rowstart2[d], re = rowstart2[d+1];
  float z0 = 0.f, z1 = 0.f;
  for (int s = rs; s < re; ++s){
    int cs = pairsrc[s];
    float2 pps = pp[cs];
    float f0 = fminf(fmaxf((pps.x - ppd.x)/denom + 0.5f, 0.f), 1.f);
    float f1 = fminf(fmaxf((pps.y - ppd.y)/denom + 0.5f, 0.f), 1.f);
    float g0 = k0 ? f0 : (1.f - f0);
    float v = fmaf(xin[cs*32 + c], scc, shc);
    z0 = fmaf(g0*(1.f-f1), v, z0);
    z1 = fmaf(g0*f1,       v, z1);
  }
  __shared__ float zsh[128];
  zsh[k0*32 + c]     = z0;
  zsh[(2+k0)*32 + c] = z1;
  __syncthreads();
  float part = 0.f;
  for (int j = 0; j < 64; ++j){
    int jj = k0*64 + j;
    part = fmaf(zsh[jj], W[jj*32 + c], part);
  }
  __shared__ float psh[64];
  psh[l] = part;
  __syncthreads();
  if (l < 32){
    float o = (psh[l] + psh[l+32]) / fmaxf((float)(re - rs), 1.f);
    aout[d*32 + l] = eluf(o);
  }
}

// ---------------- global mean + fc ----------------
__global__ __launch_bounds__(64) void k_final(const float* __restrict__ a7, const float* __restrict__ scsh7,
                      const float* __restrict__ cnt, const float* __restrict__ fcW, float* __restrict__ outp)
{
  int b = blockIdx.x;
  int l = threadIdx.x;
  int c = l & 31, half = l >> 5;
  float sc = scsh7[c], sh = scsh7[32+c];
  float acc = 0.f, wn = 0.f;
  for (int j = half; j < GG; j += 2){
    int d = b*GG + j;
    if (cnt[d] > 0.f){ acc = fmaf(a7[d*32 + c], sc, acc + sh); wn += 1.f; }
  }
  __shared__ float sacc[64];
  __shared__ float swn[2];
  sacc[l] = acc;
  if (c == 0) swn[half] = wn;
  __syncthreads();
  if (l < 32){
    float gm = (sacc[l] + sacc[l+32]) / (swn[0] + swn[1]);
    sacc[l] = gm;
  }
  __syncthreads();
  if (l < 10){
    float o = 0.f;
    #pragma unroll
    for (int cc = 0; cc < 32; cc++) o = fmaf(sacc[cc], fcW[cc*10 + l], o);
    outp[b*10 + l] = o;
  }
}

extern "C" void kernel_launch(void* const* d_in, const int* in_sizes, int n_in,
                              void* d_out, int out_size, void* d_ws, size_t ws_size,
                              hipStream_t stream)
{
  const float*  x    = (const float*)d_in[0];
  const float2* pos  = (const float2*)d_in[1];
  const int*    ei   = (const int*)d_in[3];
  const int*    srcp = ei;
  const int*    dstp = ei + EE;
  const float2* ea   = (const float2*)d_in[4];
  const float* W1=(const float*)d_in[5],  *g1=(const float*)d_in[6],  *b1=(const float*)d_in[7];
  const float* W2=(const float*)d_in[8],  *g2=(const float*)d_in[9],  *b2=(const float*)d_in[10];
  const float* W21=(const float*)d_in[11],*g21=(const float*)d_in[12],*b21=(const float*)d_in[13];
  const float* W3=(const float*)d_in[14], *g3=(const float*)d_in[15], *b3=(const float*)d_in[16];
  const float* W4=(const float*)d_in[17], *g4=(const float*)d_in[18], *b4=(const float*)d_in[19];
  const float* W5=(const float*)d_in[20], *g5=(const float*)d_in[21], *b5=(const float*)d_in[22];
  const float* W6=(const float*)d_in[23], *g6=(const float*)d_in[24], *b6=(const float*)d_in[25];
  const float* W7=(const float*)d_in[26], *g7=(const float*)d_in[27], *b7=(const float*)d_in[28];
  const float* fcW=(const float*)d_in[29];
  float* outp = (float*)d_out;

  char* w = (char*)d_ws;
  size_t off = 0;
  auto take = [&](size_t bytes)->char*{
    char* p = w + off;
    off = (off + bytes + 255) & ~(size_t)255;
    return p;
  };
  // ---- zero region ----
  int*      deg     = (int*)      take((size_t)NN*4);
  int*      cursor  = (int*)      take((size_t)NN*4);
  unsigned char* slotb = (unsigned char*)take((size_t)NSLOT);
  float*    cnt     = (float*)    take((size_t)SS*4);
  float*    ppsum   = (float*)    take((size_t)SS*8);
  unsigned* xpkey   = (unsigned*) take((size_t)SS*32*4);
  int*      deg2    = (int*)      take((size_t)SS*4);
  int*      cursor2 = (int*)      take((size_t)SS*4);
  float*    stats   = (float*)    take(8*64*4);
  float*    tw      = (float*)    take(256);
  unsigned* mxp     = (unsigned*) take(256);
  size_t zero_bytes = off;
  // ---- written-before-read region ----
  int*      rowstart  = (int*)   take((size_t)(NN+1)*4);
  int*      rowstart2 = (int*)   take((size_t)(SS+1)*4);
  int*      bsum      = (int*)   take(1025*4);
  int*      bsum2     = (int*)   take(1025*4);
  int*      csr_src   = (int*)   take((size_t)EE*4);
  float2*   csr_f     = (float2*)take((size_t)EE*8);
  int*      pairsrc   = (int*)   take((size_t)NSLOT*4);
  int*      cid       = (int*)   take((size_t)NN*4);
  float*    scsh      = (float*) take(8*64*4);
  float2*   pp        = (float2*)take((size_t)SS*8);
  float*    xpf       = (float*) take((size_t)SS*32*4);
  float*    a6        = (float*) take((size_t)SS*32*4);
  float*    a7        = (float*) take((size_t)SS*32*4);
  float*    aP        = (float*) take((size_t)NN*16*4);
  float*    aQ        = (float*) take((size_t)NN*16*4);
  float*    aR        = (float*) take((size_t)NN*16*4);
  float*    a5        = (float*) take((size_t)NN*32*4);
  (void)ws_size; (void)in_sizes; (void)n_in; (void)out_size;

  hipMemsetAsync(d_ws, 0, zero_bytes, stream);

  // CSR build
  k_deg    <<<1024,256,0,stream>>>(dstp, deg);
  k_scan1  <<<1024,256,0,stream>>>(deg, rowstart, bsum, NN);
  k_scan2  <<<1,1024,0,stream>>>(bsum, 1024);
  k_scan3  <<<1024,256,0,stream>>>(rowstart, bsum, NN);
  k_scatter<<<1024,256,0,stream>>>(srcp, dstp, ea, rowstart, cursor, csr_src, csr_f);

  // layer 1: 10 -> 8
  k_conv<10,8,0><<<1024,256,0,stream>>>(x, nullptr, nullptr, nullptr, rowstart, csr_src, csr_f, W1, aP);
  k_stats<8,false><<<128,256,0,stream>>>(aP, nullptr, stats+0, NN);
  k_fin<<<1,32,0,stream>>>(stats+0, g1, b1, scsh+0, nullptr, (float)NN, 8);
  // layer 2: 8 -> 16
  k_conv<8,16,1><<<1024,256,0,stream>>>(aP, nullptr, scsh+0, nullptr, rowstart, csr_src, csr_f, W2, aQ);
  k_stats<16,false><<<128,256,0,stream>>>(aQ, nullptr, stats+64, NN);
  k_fin<<<1,32,0,stream>>>(stats+64, g2, b2, scsh+64, nullptr, (float)NN, 16);
  // layer 21: 16 -> 16 (skip source)
  k_conv<16,16,1><<<1024,256,0,stream>>>(aQ, nullptr, scsh+64, nullptr, rowstart, csr_src, csr_f, W21, aR);
  k_stats<16,false><<<128,256,0,stream>>>(aR, nullptr, stats+128, NN);
  k_fin<<<1,32,0,stream>>>(stats+128, g21, b21, scsh+128, nullptr, (float)NN, 16);
  // layer 3: 16 -> 16
  k_conv<16,16,1><<<1024,256,0,stream>>>(aR, nullptr, scsh+128, nullptr, rowstart, csr_src, csr_f, W3, aP);
  k_stats<16,false><<<128,256,0,stream>>>(aP, nullptr, stats+192, NN);
  k_fin<<<1,32,0,stream>>>(stats+192, g3, b3, scsh+192, nullptr, (float)NN, 16);
  // layer 4: 16 -> 16
  k_conv<16,16,1><<<1024,256,0,stream>>>(aP, nullptr, scsh+192, nullptr, rowstart, csr_src, csr_f, W4, aQ);
  k_stats<16,false><<<128,256,0,stream>>>(aQ, nullptr, stats+256, NN);
  k_fin<<<1,32,0,stream>>>(stats+256, g4, b4, scsh+256, nullptr, (float)NN, 16);
  // layer 5: (bn4(a4) + bn21(a21)) 16 -> 32
  k_conv<16,32,2><<<1024,256,0,stream>>>(aQ, aR, scsh+256, scsh+128, rowstart, csr_src, csr_f, W5, a5);
  k_stats<32,false><<<128,256,0,stream>>>(a5, nullptr, stats+320, NN);
  k_fin<<<1,32,0,stream>>>(stats+320, g5, b5, scsh+320, nullptr, (float)NN, 32);

  // pooling
  k_pool1<<<1024,256,0,stream>>>(pos, a5, scsh+320, cid, cnt, ppsum, xpkey);
  k_pool2<<<31,256,0,stream>>>(cnt, ppsum, xpkey, pp, xpf, tw);
  k_slot<<<1024,256,0,stream>>>(srcp, dstp, cid, slotb);
  k_pair_deg<<<512,256,0,stream>>>(slotb, pp, deg2, mxp);
  k_scan1<<<31,256,0,stream>>>(deg2, rowstart2, bsum2, SS);
  k_scan2<<<1,1024,0,stream>>>(bsum2, 31);
  k_scan3<<<31,256,0,stream>>>(rowstart2, bsum2, SS);
  k_pair_fill<<<512,256,0,stream>>>(slotb, rowstart2, cursor2, pairsrc);

  // pool conv 6: 32 -> 32 (input xp, already bn5-folded)
  k_pconv<<<SS,64,0,stream>>>(xpf, nullptr, rowstart2, pairsrc, pp, (const float*)mxp, W6, a6);
  k_stats<32,true><<<128,256,0,stream>>>(a6, cnt, stats+384, SS);
  k_fin<<<1,32,0,stream>>>(stats+384, g6, b6, scsh+384, tw, 0.f, 32);
  // pool conv 7: 32 -> 32
  k_pconv<<<SS,64,0,stream>>>(a6, scsh+384, rowstart2, pairsrc, pp, (const float*)mxp, W7, a7);
  k_stats<32,true><<<128,256,0,stream>>>(a7, cnt, stats+448, SS);
  k_fin<<<1,32,0,stream>>>(stats+448, g7, b7, scsh+448, tw, 0.f, 32);

  // global mean + fc
  k_final<<<16,64,0,stream>>>(a7, scsh+448, cnt, fcW, outp);
}

// Round 2
// 2503.313 us; speedup vs baseline: 1.7540x; 1.7540x over previous
//
#include <hip/hip_runtime.h>
#include <math.h>

#define NN 262144
#define EE 2097152
#define BB 16
#define SS 7744
#define GG 484
#define NSLOT (SS*484)

__device__ __forceinline__ float eluf(float x){ return x > 0.f ? x : expm1f(x); }

// partition-XCD swizzle: physical block B -> partition p = B%16, sub i = B/16.
// XCD(B) = B%8 (round-robin heuristic) so partition p lands on XCD p%8:
// all 64 blocks of a partition share one XCD -> its 1-2 MB x-table stays L2-resident.
__device__ __forceinline__ int swiz_node(int blk, int tid){
  int p = blk & 15;
  int i = blk >> 4;
  return ((p << 6) | i) * 256 + tid;
}

// ---------------- CSR build ----------------
__global__ __launch_bounds__(256) void k_deg(const int* __restrict__ dst, int* __restrict__ deg)
{
  int gid = blockIdx.x*256 + threadIdx.x;
  int stride = gridDim.x*256;
  for (int e = gid; e < EE; e += stride) atomicAdd(&deg[__builtin_nontemporal_load(dst+e)], 1);
}

__global__ __launch_bounds__(256) void k_scan1(const int* __restrict__ in, int* __restrict__ out,
                                               int* __restrict__ bsum, int n)
{
  __shared__ int sh[256];
  int t = threadIdx.x, gid = blockIdx.x*256 + t;
  int v = (gid < n) ? in[gid] : 0;
  sh[t] = v; __syncthreads();
  for (int off=1; off<256; off<<=1){
    int tmp = (t >= off) ? sh[t-off] : 0;
    __syncthreads();
    sh[t] += tmp;
    __syncthreads();
  }
  if (gid < n) out[gid] = sh[t] - v;
  if (t == 255) bsum[blockIdx.x] = sh[255];
}

__global__ __launch_bounds__(1024) void k_scan2(int* __restrict__ bsum, int nb)
{
  __shared__ int sh[1024];
  int t = threadIdx.x;
  int v = (t < nb) ? bsum[t] : 0;
  sh[t] = v; __syncthreads();
  for (int off=1; off<1024; off<<=1){
    int tmp = (t >= off) ? sh[t-off] : 0;
    __syncthreads();
    sh[t] += tmp;
    __syncthreads();
  }
  if (t < nb) bsum[t] = sh[t] - v;
  if (t == nb-1) bsum[1024] = sh[t];
}

__global__ __launch_bounds__(256) void k_scan3(int* __restrict__ out, const int* __restrict__ bsum, int n)
{
  int gid = blockIdx.x*256 + threadIdx.x;
  if (gid < n) out[gid] += bsum[blockIdx.x];
  if (gid == 0) out[n] = bsum[1024];
}

__global__ __launch_bounds__(256) void k_scatter(const int* __restrict__ src, const int* __restrict__ dst,
                          const float2* __restrict__ ea, const int* __restrict__ rowstart,
                          int* __restrict__ cursor, int* __restrict__ csr_src, float2* __restrict__ csr_f)
{
  int gid = blockIdx.x*256 + threadIdx.x;
  int stride = gridDim.x*256;
  for (int e = gid; e < EE; e += stride){
    int d = __builtin_nontemporal_load(dst+e);
    int p = atomicAdd(&cursor[d], 1);
    int slot = rowstart[d] + p;
    csr_src[slot] = __builtin_nontemporal_load(src+e);
    float2 f = ea[e];
    f.x = fminf(fmaxf(f.x, 0.f), 1.f);
    f.y = fminf(fmaxf(f.y, 0.f), 1.f);
    csr_f[slot] = f;
  }
}

// ---------------- node spline conv (z-decomposition) ----------------
template<int CIN>
__device__ __forceinline__ void loadrow(float* xv, const float* __restrict__ xin, int srcn){
  if constexpr ((CIN & 3) == 0){
    const float4* xr = reinterpret_cast<const float4*>(xin + (size_t)srcn*CIN);
    #pragma unroll
    for (int q=0;q<CIN/4;q++){ float4 t=xr[q]; xv[4*q]=t.x; xv[4*q+1]=t.y; xv[4*q+2]=t.z; xv[4*q+3]=t.w; }
  } else {
    const float2* xr = reinterpret_cast<const float2*>(xin + (size_t)srcn*CIN);
    #pragma unroll
    for (int q=0;q<CIN/2;q++){ float2 t=xr[q]; xv[2*q]=t.x; xv[2*q+1]=t.y; }
  }
}

template<int CIN, int COUT, bool AFF>
__global__ __launch_bounds__(256) void k_conv(
    const float* __restrict__ xin, const float* __restrict__ scshA,
    const int* __restrict__ rowstart, const int* __restrict__ csr_src,
    const float2* __restrict__ csr_f, const float* __restrict__ W,
    float* __restrict__ aout)
{
  int d = swiz_node(blockIdx.x, threadIdx.x);
  float sc[CIN], sh[CIN];
  if (AFF){
    #pragma unroll
    for (int i=0;i<CIN;i++){ sc[i]=scshA[i]; sh[i]=scshA[32+i]; }
  }
  float z[4*CIN];
  #pragma unroll
  for (int j=0;j<4*CIN;j++) z[j]=0.f;
  int rs = rowstart[d], re = rowstart[d+1];

  auto accum = [&](float fx, float fy, const float* xv){
    float b0=(1.f-fx)*(1.f-fy), b1=fx*(1.f-fy), b2=(1.f-fx)*fy, b3=fx*fy;
    #pragma unroll
    for (int i=0;i<CIN;i++){
      float v = xv[i];
      if (AFF) v = fmaf(v, sc[i], sh[i]);
      z[i]       = fmaf(b0, v, z[i]);
      z[CIN+i]   = fmaf(b1, v, z[CIN+i]);
      z[2*CIN+i] = fmaf(b2, v, z[2*CIN+i]);
      z[3*CIN+i] = fmaf(b3, v, z[3*CIN+i]);
    }
  };

  union U { unsigned long long u; float2 f; };
  int s = rs;
  for (; s + 2 <= re; s += 2){
    int i0 = __builtin_nontemporal_load(csr_src + s);
    int i1 = __builtin_nontemporal_load(csr_src + s + 1);
    U u0, u1;
    u0.u = __builtin_nontemporal_load((const unsigned long long*)(csr_f + s));
    u1.u = __builtin_nontemporal_load((const unsigned long long*)(csr_f + s + 1));
    float xv0[CIN], xv1[CIN];
    loadrow<CIN>(xv0, xin, i0);
    loadrow<CIN>(xv1, xin, i1);
    accum(u0.f.x, u0.f.y, xv0);
    accum(u1.f.x, u1.f.y, xv1);
  }
  if (s < re){
    int i0 = __builtin_nontemporal_load(csr_src + s);
    U u0; u0.u = __builtin_nontemporal_load((const unsigned long long*)(csr_f + s));
    float xv0[CIN];
    loadrow<CIN>(xv0, xin, i0);
    accum(u0.f.x, u0.f.y, xv0);
  }

  float out[COUT];
  #pragma unroll
  for (int c=0;c<COUT;c++) out[c]=0.f;
  #pragma unroll
  for (int j=0;j<4*CIN;j++){
    const float* wr = W + j*COUT;
    float zj = z[j];
    #pragma unroll
    for (int c=0;c<COUT;c++) out[c] = fmaf(zj, wr[c], out[c]);
  }
  float invd = 1.f / fmaxf((float)(re - rs), 1.f);
  float4* orow = reinterpret_cast<float4*>(aout + (size_t)d*COUT);
  #pragma unroll
  for (int q=0;q<COUT/4;q++){
    float4 t;
    t.x = eluf(out[4*q+0]*invd);
    t.y = eluf(out[4*q+1]*invd);
    t.z = eluf(out[4*q+2]*invd);
    t.w = eluf(out[4*q+3]*invd);
    orow[q] = t;
  }
}

// combine two folded-BN activations into one table (input to layer 5)
__global__ __launch_bounds__(256) void k_comb(const float* __restrict__ a, const float* __restrict__ b,
    const float* __restrict__ sA, const float* __restrict__ sB, float* __restrict__ o)
{
  int n = swiz_node(blockIdx.x, threadIdx.x);
  const float4* ar = reinterpret_cast<const float4*>(a + (size_t)n*16);
  const float4* br = reinterpret_cast<const float4*>(b + (size_t)n*16);
  float4* orow = reinterpret_cast<float4*>(o + (size_t)n*16);
  #pragma unroll
  for (int q=0;q<4;q++){
    float4 av=ar[q], bv=br[q];
    float4 r;
    r.x = fmaf(av.x, sA[4*q+0], sA[32+4*q+0]) + fmaf(bv.x, sB[4*q+0], sB[32+4*q+0]);
    r.y = fmaf(av.y, sA[4*q+1], sA[32+4*q+1]) + fmaf(bv.y, sB[4*q+1], sB[32+4*q+1]);
    r.z = fmaf(av.z, sA[4*q+2], sA[32+4*q+2]) + fmaf(bv.z, sB[4*q+2], sB[32+4*q+2]);
    r.w = fmaf(av.w, sA[4*q+3], sA[32+4*q+3]) + fmaf(bv.w, sB[4*q+3], sB[32+4*q+3]);
    orow[q] = r;
  }
}

// ---------------- BN statistics (column-major coalesced) ----------------
template<int C, bool WEIGHTED>
__global__ __launch_bounds__(256) void k_stats(const float* __restrict__ a, const float* __restrict__ wcnt,
                                               float* __restrict__ stats, int n)
{
  int t = blockIdx.x*256 + threadIdx.x;
  int T = gridDim.x*256;
  float s1=0.f, s2=0.f;
  int M = n*C;
  for (int e = t; e < M; e += T){
    float v = __builtin_nontemporal_load(a+e);
    if (WEIGHTED){ if (!(wcnt[e/C] > 0.f)) continue; }
    s1 += v; s2 += v*v;
  }
  __shared__ float sh[256];
  int lt = threadIdx.x;
  sh[lt] = s1; __syncthreads();
  #pragma unroll
  for (int off=128; off>=C; off>>=1){ if (lt<off) sh[lt]+=sh[lt+off]; __syncthreads(); }
  if (lt < C) atomicAdd(&stats[lt], sh[lt]);
  __syncthreads();
  sh[lt] = s2; __syncthreads();
  #pragma unroll
  for (int off=128; off>=C; off>>=1){ if (lt<off) sh[lt]+=sh[lt+off]; __syncthreads(); }
  if (lt < C) atomicAdd(&stats[C+lt], sh[lt]);
}

__global__ void k_fin(const float* __restrict__ stats, const float* __restrict__ g,
                      const float* __restrict__ b, float* __restrict__ scsh,
                      const float* __restrict__ twp, float denomN, int C)
{
  int c = threadIdx.x;
  if (c >= C) return;
  float cntv = twp ? *twp : denomN;
  float m = stats[c] / cntv;
  float var = stats[C+c] / cntv - m*m;
  float scl = g[c] * rsqrtf(var + 1e-5f);
  scsh[c] = scl;
  scsh[32+c] = fmaf(-m, scl, b[c]);
}

// ---------------- pooling ----------------
__global__ __launch_bounds__(256) void k_pool1(const float2* __restrict__ pos, const float* __restrict__ a5,
                      const float* __restrict__ scsh5, int* __restrict__ cid,
                      float* __restrict__ cnt, float* __restrict__ ppsum, unsigned* __restrict__ xpkey)
{
  int n = swiz_node(blockIdx.x, threadIdx.x);
  float2 p = pos[n];
  const float SXf = (float)(16.0/346.0);
  const float SYf = (float)(12.0/260.0);
  int cx = (int)floorf(p.x / SXf); cx = min(max(cx, 0), 21);
  int cy = (int)floorf(p.y / SYf); cy = min(max(cy, 0), 21);
  int cd = (n >> 14) * GG + cy*22 + cx;
  cid[n] = cd;
  atomicAdd(&cnt[cd], 1.f);
  atomicAdd(&ppsum[2*cd],   p.x);
  atomicAdd(&ppsum[2*cd+1], p.y);
  const float4* ar = reinterpret_cast<const float4*>(a5 + (size_t)n*32);
  #pragma unroll
  for (int q=0;q<8;q++){
    float4 tv = ar[q];
    float vv[4] = {tv.x, tv.y, tv.z, tv.w};
    #pragma unroll
    for (int j=0;j<4;j++){
      int c = 4*q + j;
      float h = fmaf(vv[j], scsh5[c], scsh5[32+c]);
      unsigned u = __float_as_uint(h);
      unsigned key = (u & 0x80000000u) ? ~u : (u | 0x80000000u);
      atomicMax(&xpkey[cd*32 + c], key);
    }
  }
}

__global__ __launch_bounds__(256) void k_pool2(const float* __restrict__ cnt, const float* __restrict__ ppsum,
                      const unsigned* __restrict__ xpkey, float2* __restrict__ pp,
                      float* __restrict__ xpf, float* __restrict__ tw)
{
  int q = blockIdx.x*256 + threadIdx.x;
  bool act = q < SS;
  float cn = act ? cnt[q] : 0.f;
  bool val = cn > 0.f;
  if (act){
    float inv = 1.f / fmaxf(cn, 1.f);
    pp[q] = make_float2(ppsum[2*q]*inv, ppsum[2*q+1]*inv);
    #pragma unroll
    for (int c=0;c<32;c++){
      float xv = 0.f;
      if (val){
        unsigned key = xpkey[q*32+c];
        unsigned u = (key & 0x80000000u) ? (key ^ 0x80000000u) : ~key;
        xv = __uint_as_float(u);
      }
      xpf[q*32+c] = xv;
    }
  }
  unsigned long long m = __ballot(val);
  if ((threadIdx.x & 63) == 0) atomicAdd(tw, (float)__popcll(m));
}

__global__ __launch_bounds__(256) void k_slot(const int* __restrict__ src, const int* __restrict__ dst,
                      const int* __restrict__ cid, unsigned char* __restrict__ slotb)
{
  int gid = blockIdx.x*256 + threadIdx.x;
  int stride = gridDim.x*256;
  for (int e = gid; e < EE; e += stride){
    int cs = cid[__builtin_nontemporal_load(src+e)];
    int cdd = cid[__builtin_nontemporal_load(dst+e)];
    if (cs != cdd){
      int g = cs / GG;
      slotb[(size_t)cs*GG + (cdd - g*GG)] = 1;
    }
  }
}

__global__ __launch_bounds__(256) void k_pair_deg(const unsigned char* __restrict__ slotb,
                      const float2* __restrict__ pp, int* __restrict__ deg2, unsigned* __restrict__ mxp)
{
  int gid = blockIdx.x*256 + threadIdx.x;
  int stride = gridDim.x*256;
  float lm = 0.f;
  for (int s = gid; s < NSLOT; s += stride){
    if (slotb[s]){
      int cs = s / GG; int lcd = s - cs*GG;
      int g = cs / GG; int cdd = g*GG + lcd;
      atomicAdd(&deg2[cdd], 1);
      float2 a = pp[cs], b = pp[cdd];
      lm = fmaxf(lm, fmaxf(fabsf(a.x-b.x), fabsf(a.y-b.y)));
    }
  }
  __shared__ float sh[256];
  sh[threadIdx.x] = lm; __syncthreads();
  for (int off=128; off; off>>=1){ if (threadIdx.x<off) sh[threadIdx.x]=fmaxf(sh[threadIdx.x],sh[threadIdx.x+off]); __syncthreads(); }
  if (threadIdx.x==0) atomicMax(mxp, __float_as_uint(sh[0]));
}

__global__ __launch_bounds__(256) void k_pair_fill(const unsigned char* __restrict__ slotb,
                      const int* __restrict__ rowstart2, int* __restrict__ cursor2, int* __restrict__ pairsrc)
{
  int gid = blockIdx.x*256 + threadIdx.x;
  int stride = gridDim.x*256;
  for (int s = gid; s < NSLOT; s += stride){
    if (slotb[s]){
      int cs = s / GG; int lcd = s - cs*GG;
      int g = cs / GG; int cdd = g*GG + lcd;
      int p = atomicAdd(&cursor2[cdd], 1);
      pairsrc[rowstart2[cdd] + p] = cs;
    }
  }
}

// ---------------- pool spline conv: 1 wave per dst cell ----------------
__global__ __launch_bounds__(64) void k_pconv(const float* __restrict__ xin, const float* __restrict__ scsh,
                      const int* __restrict__ rowstart2, const int* __restrict__ pairsrc,
                      const float2* __restrict__ pp, const float* __restrict__ mxp,
                      const float* __restrict__ W, float* __restrict__ aout)
{
  int d = blockIdx.x;
  int l = threadIdx.x;
  int c = l & 31, k0 = l >> 5;
  float denom = 2.f * (*mxp) + 1e-12f;
  float2 ppd = pp[d];
  float scc = 1.f, shc = 0.f;
  if (scsh){ scc = scsh[c]; shc = scsh[32+c]; }
  int rs = rowstart2[d], re = rowstart2[d+1];
  float z0 = 0.f, z1 = 0.f;
  for (int s = rs; s < re; ++s){
    int cs = pairsrc[s];
    float2 pps = pp[cs];
    float f0 = fminf(fmaxf((pps.x - ppd.x)/denom + 0.5f, 0.f), 1.f);
    float f1 = fminf(fmaxf((pps.y - ppd.y)/denom + 0.5f, 0.f), 1.f);
    float g0 = k0 ? f0 : (1.f - f0);
    float v = fmaf(xin[cs*32 + c], scc, shc);
    z0 = fmaf(g0*(1.f-f1), v, z0);
    z1 = fmaf(g0*f1,       v, z1);
  }
  __shared__ float zsh[128];
  zsh[k0*32 + c]     = z0;
  zsh[(2+k0)*32 + c] = z1;
  __syncthreads();
  float part = 0.f;
  for (int j = 0; j < 64; ++j){
    int jj = k0*64 + j;
    part = fmaf(zsh[jj], W[jj*32 + c], part);
  }
  __shared__ float psh[64];
  psh[l] = part;
  __syncthreads();
  if (l < 32){
    float o = (psh[l] + psh[l+32]) / fmaxf((float)(re - rs), 1.f);
    aout[d*32 + l] = eluf(o);
  }
}

// ---------------- global mean + fc ----------------
__global__ __launch_bounds__(64) void k_final(const float* __restrict__ a7, const float* __restrict__ scsh7,
                      const float* __restrict__ cnt, const float* __restrict__ fcW, float* __restrict__ outp)
{
  int b = blockIdx.x;
  int l = threadIdx.x;
  int c = l & 31, half = l >> 5;
  float sc = scsh7[c], sh = scsh7[32+c];
  float acc = 0.f, wn = 0.f;
  for (int j = half; j < GG; j += 2){
    int d = b*GG + j;
    if (cnt[d] > 0.f){ acc = fmaf(a7[d*32 + c], sc, acc + sh); wn += 1.f; }
  }
  __shared__ float sacc[64];
  __shared__ float swn[2];
  sacc[l] = acc;
  if (c == 0) swn[half] = wn;
  __syncthreads();
  if (l < 32){
    float gm = (sacc[l] + sacc[l+32]) / (swn[0] + swn[1]);
    sacc[l] = gm;
  }
  __syncthreads();
  if (l < 10){
    float o = 0.f;
    #pragma unroll
    for (int cc = 0; cc < 32; cc++) o = fmaf(sacc[cc], fcW[cc*10 + l], o);
    outp[b*10 + l] = o;
  }
}

extern "C" void kernel_launch(void* const* d_in, const int* in_sizes, int n_in,
                              void* d_out, int out_size, void* d_ws, size_t ws_size,
                              hipStream_t stream)
{
  const float*  x    = (const float*)d_in[0];
  const float2* pos  = (const float2*)d_in[1];
  const int*    ei   = (const int*)d_in[3];
  const int*    srcp = ei;
  const int*    dstp = ei + EE;
  const float2* ea   = (const float2*)d_in[4];
  const float* W1=(const float*)d_in[5],  *g1=(const float*)d_in[6],  *b1=(const float*)d_in[7];
  const float* W2=(const float*)d_in[8],  *g2=(const float*)d_in[9],  *b2=(const float*)d_in[10];
  const float* W21=(const float*)d_in[11],*g21=(const float*)d_in[12],*b21=(const float*)d_in[13];
  const float* W3=(const float*)d_in[14], *g3=(const float*)d_in[15], *b3=(const float*)d_in[16];
  const float* W4=(const float*)d_in[17], *g4=(const float*)d_in[18], *b4=(const float*)d_in[19];
  const float* W5=(const float*)d_in[20], *g5=(const float*)d_in[21], *b5=(const float*)d_in[22];
  const float* W6=(const float*)d_in[23], *g6=(const float*)d_in[24], *b6=(const float*)d_in[25];
  const float* W7=(const float*)d_in[26], *g7=(const float*)d_in[27], *b7=(const float*)d_in[28];
  const float* fcW=(const float*)d_in[29];
  float* outp = (float*)d_out;

  char* w = (char*)d_ws;
  size_t off = 0;
  auto take = [&](size_t bytes)->char*{
    char* p = w + off;
    off = (off + bytes + 255) & ~(size_t)255;
    return p;
  };
  // ---- zero region ----
  int*      deg     = (int*)      take((size_t)NN*4);
  int*      cursor  = (int*)      take((size_t)NN*4);
  unsigned char* slotb = (unsigned char*)take((size_t)NSLOT);
  float*    cnt     = (float*)    take((size_t)SS*4);
  float*    ppsum   = (float*)    take((size_t)SS*8);
  unsigned* xpkey   = (unsigned*) take((size_t)SS*32*4);
  int*      deg2    = (int*)      take((size_t)SS*4);
  int*      cursor2 = (int*)      take((size_t)SS*4);
  float*    stats   = (float*)    take(8*64*4);
  float*    tw      = (float*)    take(256);
  unsigned* mxp     = (unsigned*) take(256);
  size_t zero_bytes = off;
  // ---- written-before-read region ----
  int*      rowstart  = (int*)   take((size_t)(NN+1)*4);
  int*      rowstart2 = (int*)   take((size_t)(SS+1)*4);
  int*      bsum      = (int*)   take(1025*4);
  int*      bsum2     = (int*)   take(1025*4);
  int*      csr_src   = (int*)   take((size_t)EE*4);
  float2*   csr_f     = (float2*)take((size_t)EE*8);
  int*      pairsrc   = (int*)   take((size_t)NSLOT*4);
  int*      cid       = (int*)   take((size_t)NN*4);
  float*    scsh      = (float*) take(8*64*4);
  float2*   pp        = (float2*)take((size_t)SS*8);
  float*    xpf       = (float*) take((size_t)SS*32*4);
  float*    a6        = (float*) take((size_t)SS*32*4);
  float*    a7        = (float*) take((size_t)SS*32*4);
  float*    aP        = (float*) take((size_t)NN*16*4);
  float*    aQ        = (float*) take((size_t)NN*16*4);
  float*    aR        = (float*) take((size_t)NN*16*4);
  float*    a5        = (float*) take((size_t)NN*32*4);
  (void)ws_size; (void)in_sizes; (void)n_in; (void)out_size;

  hipMemsetAsync(d_ws, 0, zero_bytes, stream);

  // CSR build
  k_deg    <<<1024,256,0,stream>>>(dstp, deg);
  k_scan1  <<<1024,256,0,stream>>>(deg, rowstart, bsum, NN);
  k_scan2  <<<1,1024,0,stream>>>(bsum, 1024);
  k_scan3  <<<1024,256,0,stream>>>(rowstart, bsum, NN);
  k_scatter<<<1024,256,0,stream>>>(srcp, dstp, ea, rowstart, cursor, csr_src, csr_f);

  // layer 1: 10 -> 8
  k_conv<10,8,false><<<1024,256,0,stream>>>(x, nullptr, rowstart, csr_src, csr_f, W1, aP);
  k_stats<8,false><<<128,256,0,stream>>>(aP, nullptr, stats+0, NN);
  k_fin<<<1,32,0,stream>>>(stats+0, g1, b1, scsh+0, nullptr, (float)NN, 8);
  // layer 2: 8 -> 16
  k_conv<8,16,true><<<1024,256,0,stream>>>(aP, scsh+0, rowstart, csr_src, csr_f, W2, aQ);
  k_stats<16,false><<<128,256,0,stream>>>(aQ, nullptr, stats+64, NN);
  k_fin<<<1,32,0,stream>>>(stats+64, g2, b2, scsh+64, nullptr, (float)NN, 16);
  // layer 21: 16 -> 16 (skip source)
  k_conv<16,16,true><<<1024,256,0,stream>>>(aQ, scsh+64, rowstart, csr_src, csr_f, W21, aR);
  k_stats<16,false><<<128,256,0,stream>>>(aR, nullptr, stats+128, NN);
  k_fin<<<1,32,0,stream>>>(stats+128, g21, b21, scsh+128, nullptr, (float)NN, 16);
  // layer 3: 16 -> 16
  k_conv<16,16,true><<<1024,256,0,stream>>>(aR, scsh+128, rowstart, csr_src, csr_f, W3, aP);
  k_stats<16,false><<<128,256,0,stream>>>(aP, nullptr, stats+192, NN);
  k_fin<<<1,32,0,stream>>>(stats+192, g3, b3, scsh+192, nullptr, (float)NN, 16);
  // layer 4: 16 -> 16
  k_conv<16,16,true><<<1024,256,0,stream>>>(aP, scsh+192, rowstart, csr_src, csr_f, W4, aQ);
  k_stats<16,false><<<128,256,0,stream>>>(aQ, nullptr, stats+256, NN);
  k_fin<<<1,32,0,stream>>>(stats+256, g4, b4, scsh+256, nullptr, (float)NN, 16);
  // combine bn4(a4)+bn21(a21) -> aP (aP's old contents dead), then layer 5: 16 -> 32
  k_comb<<<1024,256,0,stream>>>(aQ, aR, scsh+256, scsh+128, aP);
  k_conv<16,32,false><<<1024,256,0,stream>>>(aP, nullptr, rowstart, csr_src, csr_f, W5, a5);
  k_stats<32,false><<<128,256,0,stream>>>(a5, nullptr, stats+320, NN);
  k_fin<<<1,32,0,stream>>>(stats+320, g5, b5, scsh+320, nullptr, (float)NN, 32);

  // pooling
  k_pool1<<<1024,256,0,stream>>>(pos, a5, scsh+320, cid, cnt, ppsum, xpkey);
  k_pool2<<<31,256,0,stream>>>(cnt, ppsum, xpkey, pp, xpf, tw);
  k_slot<<<1024,256,0,stream>>>(srcp, dstp, cid, slotb);
  k_pair_deg<<<512,256,0,stream>>>(slotb, pp, deg2, mxp);
  k_scan1<<<31,256,0,stream>>>(deg2, rowstart2, bsum2, SS);
  k_scan2<<<1,1024,0,stream>>>(bsum2, 31);
  k_scan3<<<31,256,0,stream>>>(rowstart2, bsum2, SS);
  k_pair_fill<<<512,256,0,stream>>>(slotb, rowstart2, cursor2, pairsrc);

  // pool conv 6: 32 -> 32 (input xp, already bn5-folded)
  k_pconv<<<SS,64,0,stream>>>(xpf, nullptr, rowstart2, pairsrc, pp, (const float*)mxp, W6, a6);
  k_stats<32,true><<<128,256,0,stream>>>(a6, cnt, stats+384, SS);
  k_fin<<<1,32,0,stream>>>(stats+384, g6, b6, scsh+384, tw, 0.f, 32);
  // pool conv 7: 32 -> 32
  k_pconv<<<SS,64,0,stream>>>(a6, scsh+384, rowstart2, pairsrc, pp, (const float*)mxp, W7, a7);
  k_stats<32,true><<<128,256,0,stream>>>(a7, cnt, stats+448, SS);
  k_fin<<<1,32,0,stream>>>(stats+448, g7, b7, scsh+448, tw, 0.f, 32);

  // global mean + fc
  k_final<<<16,64,0,stream>>>(a7, scsh+448, cnt, fcW, outp);
}

// Round 3
// 1669.613 us; speedup vs baseline: 2.6299x; 1.4993x over previous
//
#include <hip/hip_runtime.h>
#include <math.h>

#define NN 262144
#define EE 2097152
#define BB 16
#define SS 7744
#define GG 484
#define NSLOT (SS*484)

__device__ __forceinline__ float eluf(float x){ return x > 0.f ? x : expm1f(x); }

// ---------------- CSR build ----------------
__global__ __launch_bounds__(256) void k_deg(const int* __restrict__ dst, int* __restrict__ deg)
{
  int gid = blockIdx.x*256 + threadIdx.x;
  int stride = gridDim.x*256;
  for (int e = gid; e < EE; e += stride) atomicAdd(&deg[__builtin_nontemporal_load(dst+e)], 1);
}

__global__ __launch_bounds__(256) void k_scan1(const int* __restrict__ in, int* __restrict__ out,
                                               int* __restrict__ bsum, int n)
{
  __shared__ int sh[256];
  int t = threadIdx.x, gid = blockIdx.x*256 + t;
  int v = (gid < n) ? in[gid] : 0;
  sh[t] = v; __syncthreads();
  for (int off=1; off<256; off<<=1){
    int tmp = (t >= off) ? sh[t-off] : 0;
    __syncthreads();
    sh[t] += tmp;
    __syncthreads();
  }
  if (gid < n) out[gid] = sh[t] - v;
  if (t == 255) bsum[blockIdx.x] = sh[255];
}

__global__ __launch_bounds__(1024) void k_scan2(int* __restrict__ bsum, int nb)
{
  __shared__ int sh[1024];
  int t = threadIdx.x;
  int v = (t < nb) ? bsum[t] : 0;
  sh[t] = v; __syncthreads();
  for (int off=1; off<1024; off<<=1){
    int tmp = (t >= off) ? sh[t-off] : 0;
    __syncthreads();
    sh[t] += tmp;
    __syncthreads();
  }
  if (t < nb) bsum[t] = sh[t] - v;
  if (t == nb-1) bsum[1024] = sh[t];
}

__global__ __launch_bounds__(256) void k_scan3(int* __restrict__ out, const int* __restrict__ bsum, int n)
{
  int gid = blockIdx.x*256 + threadIdx.x;
  if (gid < n) out[gid] += bsum[blockIdx.x];
  if (gid == 0) out[n] = bsum[1024];
}

__global__ __launch_bounds__(256) void k_scatter(const int* __restrict__ src, const int* __restrict__ dst,
                          const float2* __restrict__ ea, const int* __restrict__ rowstart,
                          int* __restrict__ cursor, int* __restrict__ csr_src, float2* __restrict__ csr_f)
{
  int gid = blockIdx.x*256 + threadIdx.x;
  int stride = gridDim.x*256;
  for (int e = gid; e < EE; e += stride){
    int d = __builtin_nontemporal_load(dst+e);
    int p = atomicAdd(&cursor[d], 1);
    int slot = rowstart[d] + p;
    csr_src[slot] = __builtin_nontemporal_load(src+e);
    float2 f = ea[e];
    f.x = fminf(fmaxf(f.x, 0.f), 1.f);
    f.y = fminf(fmaxf(f.y, 0.f), 1.f);
    csr_f[slot] = f;
  }
}

// ---------------- node spline conv (z-decomposition, 2 threads per node) ----------------
template<int CIN>
__device__ __forceinline__ void loadrow(float* xv, const float* __restrict__ xin, int srcn){
  if constexpr ((CIN & 3) == 0){
    const float4* xr = reinterpret_cast<const float4*>(xin + (size_t)srcn*CIN);
    #pragma unroll
    for (int q=0;q<CIN/4;q++){ float4 t=xr[q]; xv[4*q]=t.x; xv[4*q+1]=t.y; xv[4*q+2]=t.z; xv[4*q+3]=t.w; }
  } else {
    const float2* xr = reinterpret_cast<const float2*>(xin + (size_t)srcn*CIN);
    #pragma unroll
    for (int q=0;q<CIN/2;q++){ float2 t=xr[q]; xv[2*q]=t.x; xv[2*q+1]=t.y; }
  }
}

// grid: 2048 blocks x 256 threads; 128 nodes/block, 2 threads/node (edge halves).
// partition-XCD swizzle preserved: partition p = blk & 15.
template<int CIN, int COUT, bool AFF>
__global__ __launch_bounds__(256) void k_conv(
    const float* __restrict__ xin, const float* __restrict__ scshA,
    const int* __restrict__ rowstart, const int* __restrict__ csr_src,
    const float2* __restrict__ csr_f, const float* __restrict__ W,
    float* __restrict__ aout)
{
  int tid = threadIdx.x;
  int h = tid & 1;
  int lnode = tid >> 1;
  int p = blockIdx.x & 15;
  int i = blockIdx.x >> 4;                 // [0,128)
  int d = (p << 14) + i*128 + lnode;
  float sc[CIN], sh[CIN];
  if (AFF){
    #pragma unroll
    for (int k=0;k<CIN;k++){ sc[k]=scshA[k]; sh[k]=scshA[32+k]; }
  }
  float z[4*CIN];
  #pragma unroll
  for (int j=0;j<4*CIN;j++) z[j]=0.f;
  int rs = rowstart[d], re = rowstart[d+1];

  auto accum = [&](float fx, float fy, const float* xv){
    float b0=(1.f-fx)*(1.f-fy), b1=fx*(1.f-fy), b2=(1.f-fx)*fy, b3=fx*fy;
    #pragma unroll
    for (int k=0;k<CIN;k++){
      float v = xv[k];
      if (AFF) v = fmaf(v, sc[k], sh[k]);
      z[k]       = fmaf(b0, v, z[k]);
      z[CIN+k]   = fmaf(b1, v, z[CIN+k]);
      z[2*CIN+k] = fmaf(b2, v, z[2*CIN+k]);
      z[3*CIN+k] = fmaf(b3, v, z[3*CIN+k]);
    }
  };

  union U { unsigned long long u; float2 f; };
  int s = rs + h;                          // this thread's edges: rs+h, rs+h+2, ...
  for (; s + 2 < re; s += 4){
    int i0 = __builtin_nontemporal_load(csr_src + s);
    int i1 = __builtin_nontemporal_load(csr_src + s + 2);
    U u0, u1;
    u0.u = __builtin_nontemporal_load((const unsigned long long*)(csr_f + s));
    u1.u = __builtin_nontemporal_load((const unsigned long long*)(csr_f + s + 2));
    float xv0[CIN], xv1[CIN];
    loadrow<CIN>(xv0, xin, i0);
    loadrow<CIN>(xv1, xin, i1);
    accum(u0.f.x, u0.f.y, xv0);
    accum(u1.f.x, u1.f.y, xv1);
  }
  if (s < re){
    int i0 = __builtin_nontemporal_load(csr_src + s);
    U u0; u0.u = __builtin_nontemporal_load((const unsigned long long*)(csr_f + s));
    float xv0[CIN];
    loadrow<CIN>(xv0, xin, i0);
    accum(u0.f.x, u0.f.y, xv0);
  }

  float out[COUT];
  #pragma unroll
  for (int c=0;c<COUT;c++) out[c]=0.f;
  #pragma unroll
  for (int j=0;j<4*CIN;j++){
    const float* wr = W + j*COUT;
    float zj = z[j];
    #pragma unroll
    for (int c=0;c<COUT;c++) out[c] = fmaf(zj, wr[c], out[c]);
  }
  // combine the two halves' partial results (lanes 2k <-> 2k+1)
  #pragma unroll
  for (int c=0;c<COUT;c++) out[c] += __shfl_xor(out[c], 1, 64);

  float invd = 1.f / fmaxf((float)(re - rs), 1.f);
  // each half stores half the output row
  float4* orow = reinterpret_cast<float4*>(aout + (size_t)d*COUT + h*(COUT/2));
  #pragma unroll
  for (int q=0;q<COUT/8;q++){
    float4 t;
    t.x = eluf(out[h*(COUT/2)+4*q+0]*invd);
    t.y = eluf(out[h*(COUT/2)+4*q+1]*invd);
    t.z = eluf(out[h*(COUT/2)+4*q+2]*invd);
    t.w = eluf(out[h*(COUT/2)+4*q+3]*invd);
    orow[q] = t;
  }
}

// combine two folded-BN activations into one table (input to layer 5)
__global__ __launch_bounds__(256) void k_comb(const float* __restrict__ a, const float* __restrict__ b,
    const float* __restrict__ sA, const float* __restrict__ sB, float* __restrict__ o)
{
  int n = blockIdx.x*256 + threadIdx.x;
  const float4* ar = reinterpret_cast<const float4*>(a + (size_t)n*16);
  const float4* br = reinterpret_cast<const float4*>(b + (size_t)n*16);
  float4* orow = reinterpret_cast<float4*>(o + (size_t)n*16);
  #pragma unroll
  for (int q=0;q<4;q++){
    float4 av=ar[q], bv=br[q];
    float4 r;
    r.x = fmaf(av.x, sA[4*q+0], sA[32+4*q+0]) + fmaf(bv.x, sB[4*q+0], sB[32+4*q+0]);
    r.y = fmaf(av.y, sA[4*q+1], sA[32+4*q+1]) + fmaf(bv.y, sB[4*q+1], sB[32+4*q+1]);
    r.z = fmaf(av.z, sA[4*q+2], sA[32+4*q+2]) + fmaf(bv.z, sB[4*q+2], sB[32+4*q+2]);
    r.w = fmaf(av.w, sA[4*q+3], sA[32+4*q+3]) + fmaf(bv.w, sB[4*q+3], sB[32+4*q+3]);
    orow[q] = r;
  }
}

// ---------------- BN statistics (column-major coalesced) ----------------
template<int C, bool WEIGHTED>
__global__ __launch_bounds__(256) void k_stats(const float* __restrict__ a, const float* __restrict__ wcnt,
                                               float* __restrict__ stats, int n)
{
  int t = blockIdx.x*256 + threadIdx.x;
  int T = gridDim.x*256;
  float s1=0.f, s2=0.f;
  int M = n*C;
  for (int e = t; e < M; e += T){
    float v = __builtin_nontemporal_load(a+e);
    if (WEIGHTED){ if (!(wcnt[e/C] > 0.f)) continue; }
    s1 += v; s2 += v*v;
  }
  __shared__ float sh[256];
  int lt = threadIdx.x;
  sh[lt] = s1; __syncthreads();
  #pragma unroll
  for (int off=128; off>=C; off>>=1){ if (lt<off) sh[lt]+=sh[lt+off]; __syncthreads(); }
  if (lt < C) atomicAdd(&stats[lt], sh[lt]);
  __syncthreads();
  sh[lt] = s2; __syncthreads();
  #pragma unroll
  for (int off=128; off>=C; off>>=1){ if (lt<off) sh[lt]+=sh[lt+off]; __syncthreads(); }
  if (lt < C) atomicAdd(&stats[C+lt], sh[lt]);
}

__global__ void k_fin(const float* __restrict__ stats, const float* __restrict__ g,
                      const float* __restrict__ b, float* __restrict__ scsh,
                      const float* __restrict__ twp, float denomN, int C)
{
  int c = threadIdx.x;
  if (c >= C) return;
  float cntv = twp ? *twp : denomN;
  float m = stats[c] / cntv;
  float var = stats[C+c] / cntv - m*m;
  float scl = g[c] * rsqrtf(var + 1e-5f);
  scsh[c] = scl;
  scsh[32+c] = fmaf(-m, scl, b[c]);
}

// ---------------- pooling: counting sort by cell, then wave-per-cell gather ----------------
__global__ __launch_bounds__(256) void k_cellhist(const float2* __restrict__ pos,
                      int* __restrict__ cid, int* __restrict__ hist)
{
  int n = blockIdx.x*256 + threadIdx.x;
  float2 p = pos[n];
  const float SXf = (float)(16.0/346.0);
  const float SYf = (float)(12.0/260.0);
  int cx = (int)floorf(p.x / SXf); cx = min(max(cx, 0), 21);
  int cy = (int)floorf(p.y / SYf); cy = min(max(cy, 0), 21);
  int cd = (n >> 14) * GG + cy*22 + cx;
  cid[n] = cd;
  atomicAdd(&hist[cd], 1);
}

__global__ __launch_bounds__(256) void k_cellscatter(const int* __restrict__ cid,
                      const int* __restrict__ cellstart, int* __restrict__ ccur, int* __restrict__ order)
{
  int n = blockIdx.x*256 + threadIdx.x;
  int cd = cid[n];
  int t = atomicAdd(&ccur[cd], 1);
  order[cellstart[cd] + t] = n;
}

// wave per cell: segment-max (bn5 folded per element), pos-sum, cnt, tw. Zero heavy atomics.
__global__ __launch_bounds__(256) void k_poolg(const int* __restrict__ cellstart, const int* __restrict__ order,
    const float2* __restrict__ pos, const float* __restrict__ a5, const float* __restrict__ scsh5,
    float* __restrict__ xpf, float2* __restrict__ pp, float* __restrict__ cntf, float* __restrict__ tw)
{
  int q = blockIdx.x*4 + (threadIdx.x >> 6);
  if (q >= SS) return;
  int l = threadIdx.x & 63;
  int c = l & 31, h = l >> 5;
  int rs = cellstart[q], re = cellstart[q+1];
  float sc = scsh5[c], sh = scsh5[32+c];
  float m = -3.4e38f, ps = 0.f;
  for (int j = rs + h; j < re; j += 2){
    int n = __builtin_nontemporal_load(order + j);
    float v = fmaf(__builtin_nontemporal_load(a5 + (size_t)n*32 + c), sc, sh);
    m = fmaxf(m, v);
    if (c < 2) ps += ((const float*)pos)[2*(size_t)n + c];
  }
  m = fmaxf(m, __shfl_xor(m, 32, 64));
  ps += __shfl_xor(ps, 32, 64);
  int cnt = re - rs;
  if (h == 0) xpf[(size_t)q*32 + c] = (cnt > 0) ? m : 0.f;
  if (l < 2) ((float*)pp)[2*(size_t)q + l] = ps / fmaxf((float)cnt, 1.f);
  if (l == 2) cntf[q] = (float)cnt;
  if (l == 3 && cnt > 0) atomicAdd(tw, 1.f);
}

__global__ __launch_bounds__(256) void k_slot(const int* __restrict__ src, const int* __restrict__ dst,
                      const int* __restrict__ cid, unsigned char* __restrict__ slotb)
{
  int gid = blockIdx.x*256 + threadIdx.x;
  int stride = gridDim.x*256;
  for (int e = gid; e < EE; e += stride){
    int cs = cid[__builtin_nontemporal_load(src+e)];
    int cdd = cid[__builtin_nontemporal_load(dst+e)];
    if (cs != cdd){
      int g = cs / GG;
      slotb[(size_t)cs*GG + (cdd - g*GG)] = 1;
    }
  }
}

__global__ __launch_bounds__(256) void k_pair_deg(const unsigned char* __restrict__ slotb,
                      const float2* __restrict__ pp, int* __restrict__ deg2, unsigned* __restrict__ mxp)
{
  int gid = blockIdx.x*256 + threadIdx.x;
  int stride = gridDim.x*256;
  float lm = 0.f;
  for (int s = gid; s < NSLOT; s += stride){
    if (slotb[s]){
      int cs = s / GG; int lcd = s - cs*GG;
      int g = cs / GG; int cdd = g*GG + lcd;
      atomicAdd(&deg2[cdd], 1);
      float2 a = pp[cs], b = pp[cdd];
      lm = fmaxf(lm, fmaxf(fabsf(a.x-b.x), fabsf(a.y-b.y)));
    }
  }
  __shared__ float sh[256];
  sh[threadIdx.x] = lm; __syncthreads();
  for (int off=128; off; off>>=1){ if (threadIdx.x<off) sh[threadIdx.x]=fmaxf(sh[threadIdx.x],sh[threadIdx.x+off]); __syncthreads(); }
  if (threadIdx.x==0) atomicMax(mxp, __float_as_uint(sh[0]));
}

__global__ __launch_bounds__(256) void k_pair_fill(const unsigned char* __restrict__ slotb,
                      const int* __restrict__ rowstart2, int* __restrict__ cursor2, int* __restrict__ pairsrc)
{
  int gid = blockIdx.x*256 + threadIdx.x;
  int stride = gridDim.x*256;
  for (int s = gid; s < NSLOT; s += stride){
    if (slotb[s]){
      int cs = s / GG; int lcd = s - cs*GG;
      int g = cs / GG; int cdd = g*GG + lcd;
      int p = atomicAdd(&cursor2[cdd], 1);
      pairsrc[rowstart2[cdd] + p] = cs;
    }
  }
}

// ---------------- pool spline conv: 1 wave per dst cell ----------------
__global__ __launch_bounds__(64) void k_pconv(const float* __restrict__ xin, const float* __restrict__ scsh,
                      const int* __restrict__ rowstart2, const int* __restrict__ pairsrc,
                      const float2* __restrict__ pp, const float* __restrict__ mxp,
                      const float* __restrict__ W, float* __restrict__ aout)
{
  int d = blockIdx.x;
  int l = threadIdx.x;
  int c = l & 31, k0 = l >> 5;
  float denom = 2.f * (*mxp) + 1e-12f;
  float2 ppd = pp[d];
  float scc = 1.f, shc = 0.f;
  if (scsh){ scc = scsh[c]; shc = scsh[32+c]; }
  int rs = rowstart2[d], re = rowstart2[d+1];
  float z0 = 0.f, z1 = 0.f;
  for (int s = rs; s < re; ++s){
    int cs = pairsrc[s];
    float2 pps = pp[cs];
    float f0 = fminf(fmaxf((pps.x - ppd.x)/denom + 0.5f, 0.f), 1.f);
    float f1 = fminf(fmaxf((pps.y - ppd.y)/denom + 0.5f, 0.f), 1.f);
    float g0 = k0 ? f0 : (1.f - f0);
    float v = fmaf(xin[cs*32 + c], scc, shc);
    z0 = fmaf(g0*(1.f-f1), v, z0);
    z1 = fmaf(g0*f1,       v, z1);
  }
  __shared__ float zsh[128];
  zsh[k0*32 + c]     = z0;
  zsh[(2+k0)*32 + c] = z1;
  __syncthreads();
  float part = 0.f;
  for (int j = 0; j < 64; ++j){
    int jj = k0*64 + j;
    part = fmaf(zsh[jj], W[jj*32 + c], part);
  }
  __shared__ float psh[64];
  psh[l] = part;
  __syncthreads();
  if (l < 32){
    float o = (psh[l] + psh[l+32]) / fmaxf((float)(re - rs), 1.f);
    aout[d*32 + l] = eluf(o);
  }
}

// ---------------- global mean + fc ----------------
__global__ __launch_bounds__(64) void k_final(const float* __restrict__ a7, const float* __restrict__ scsh7,
                      const float* __restrict__ cnt, const float* __restrict__ fcW, float* __restrict__ outp)
{
  int b = blockIdx.x;
  int l = threadIdx.x;
  int c = l & 31, half = l >> 5;
  float sc = scsh7[c], sh = scsh7[32+c];
  float acc = 0.f, wn = 0.f;
  for (int j = half; j < GG; j += 2){
    int d = b*GG + j;
    if (cnt[d] > 0.f){ acc = fmaf(a7[d*32 + c], sc, acc + sh); wn += 1.f; }
  }
  __shared__ float sacc[64];
  __shared__ float swn[2];
  sacc[l] = acc;
  if (c == 0) swn[half] = wn;
  __syncthreads();
  if (l < 32){
    float gm = (sacc[l] + sacc[l+32]) / (swn[0] + swn[1]);
    sacc[l] = gm;
  }
  __syncthreads();
  if (l < 10){
    float o = 0.f;
    #pragma unroll
    for (int cc = 0; cc < 32; cc++) o = fmaf(sacc[cc], fcW[cc*10 + l], o);
    outp[b*10 + l] = o;
  }
}

extern "C" void kernel_launch(void* const* d_in, const int* in_sizes, int n_in,
                              void* d_out, int out_size, void* d_ws, size_t ws_size,
                              hipStream_t stream)
{
  const float*  x    = (const float*)d_in[0];
  const float2* pos  = (const float2*)d_in[1];
  const int*    ei   = (const int*)d_in[3];
  const int*    srcp = ei;
  const int*    dstp = ei + EE;
  const float2* ea   = (const float2*)d_in[4];
  const float* W1=(const float*)d_in[5],  *g1=(const float*)d_in[6],  *b1=(const float*)d_in[7];
  const float* W2=(const float*)d_in[8],  *g2=(const float*)d_in[9],  *b2=(const float*)d_in[10];
  const float* W21=(const float*)d_in[11],*g21=(const float*)d_in[12],*b21=(const float*)d_in[13];
  const float* W3=(const float*)d_in[14], *g3=(const float*)d_in[15], *b3=(const float*)d_in[16];
  const float* W4=(const float*)d_in[17], *g4=(const float*)d_in[18], *b4=(const float*)d_in[19];
  const float* W5=(const float*)d_in[20], *g5=(const float*)d_in[21], *b5=(const float*)d_in[22];
  const float* W6=(const float*)d_in[23], *g6=(const float*)d_in[24], *b6=(const float*)d_in[25];
  const float* W7=(const float*)d_in[26], *g7=(const float*)d_in[27], *b7=(const float*)d_in[28];
  const float* fcW=(const float*)d_in[29];
  float* outp = (float*)d_out;

  char* w = (char*)d_ws;
  size_t off = 0;
  auto take = [&](size_t bytes)->char*{
    char* p = w + off;
    off = (off + bytes + 255) & ~(size_t)255;
    return p;
  };
  // ---- zero region ----
  int*      deg     = (int*)      take((size_t)NN*4);
  int*      cursor  = (int*)      take((size_t)NN*4);
  unsigned char* slotb = (unsigned char*)take((size_t)NSLOT);
  int*      hist    = (int*)      take((size_t)SS*4);
  int*      ccur    = (int*)      take((size_t)SS*4);
  int*      deg2    = (int*)      take((size_t)SS*4);
  int*      cursor2 = (int*)      take((size_t)SS*4);
  float*    stats   = (float*)    take(8*64*4);
  float*    tw      = (float*)    take(256);
  unsigned* mxp     = (unsigned*) take(256);
  size_t zero_bytes = off;
  // ---- written-before-read region ----
  int*      rowstart  = (int*)   take((size_t)(NN+1)*4);
  int*      rowstart2 = (int*)   take((size_t)(SS+1)*4);
  int*      cellstart = (int*)   take((size_t)(SS+1)*4);
  int*      bsum      = (int*)   take(1025*4);
  int*      bsum2     = (int*)   take(1025*4);
  int*      bsum3     = (int*)   take(1025*4);
  int*      csr_src   = (int*)   take((size_t)EE*4);
  float2*   csr_f     = (float2*)take((size_t)EE*8);
  int*      pairsrc   = (int*)   take((size_t)NSLOT*4);
  int*      cid       = (int*)   take((size_t)NN*4);
  int*      order     = (int*)   take((size_t)NN*4);
  float*    scsh      = (float*) take(8*64*4);
  float2*   pp        = (float2*)take((size_t)SS*8);
  float*    xpf       = (float*) take((size_t)SS*32*4);
  float*    cntf      = (float*) take((size_t)SS*4);
  float*    a6        = (float*) take((size_t)SS*32*4);
  float*    a7        = (float*) take((size_t)SS*32*4);
  float*    aP        = (float*) take((size_t)NN*16*4);
  float*    aQ        = (float*) take((size_t)NN*16*4);
  float*    aR        = (float*) take((size_t)NN*16*4);
  float*    a5        = (float*) take((size_t)NN*32*4);
  (void)ws_size; (void)in_sizes; (void)n_in; (void)out_size;

  hipMemsetAsync(d_ws, 0, zero_bytes, stream);

  // CSR build (by dst)
  k_deg    <<<1024,256,0,stream>>>(dstp, deg);
  k_scan1  <<<1024,256,0,stream>>>(deg, rowstart, bsum, NN);
  k_scan2  <<<1,1024,0,stream>>>(bsum, 1024);
  k_scan3  <<<1024,256,0,stream>>>(rowstart, bsum, NN);
  k_scatter<<<1024,256,0,stream>>>(srcp, dstp, ea, rowstart, cursor, csr_src, csr_f);

  // cell assignment + counting sort of nodes by cell (for pooling)
  k_cellhist   <<<1024,256,0,stream>>>(pos, cid, hist);
  k_scan1      <<<31,256,0,stream>>>(hist, cellstart, bsum3, SS);
  k_scan2      <<<1,1024,0,stream>>>(bsum3, 31);
  k_scan3      <<<31,256,0,stream>>>(cellstart, bsum3, SS);
  k_cellscatter<<<1024,256,0,stream>>>(cid, cellstart, ccur, order);
  k_slot       <<<1024,256,0,stream>>>(srcp, dstp, cid, slotb);

  // layer 1: 10 -> 8
  k_conv<10,8,false><<<2048,256,0,stream>>>(x, nullptr, rowstart, csr_src, csr_f, W1, aP);
  k_stats<8,false><<<128,256,0,stream>>>(aP, nullptr, stats+0, NN);
  k_fin<<<1,32,0,stream>>>(stats+0, g1, b1, scsh+0, nullptr, (float)NN, 8);
  // layer 2: 8 -> 16
  k_conv<8,16,true><<<2048,256,0,stream>>>(aP, scsh+0, rowstart, csr_src, csr_f, W2, aQ);
  k_stats<16,false><<<128,256,0,stream>>>(aQ, nullptr, stats+64, NN);
  k_fin<<<1,32,0,stream>>>(stats+64, g2, b2, scsh+64, nullptr, (float)NN, 16);
  // layer 21: 16 -> 16 (skip source)
  k_conv<16,16,true><<<2048,256,0,stream>>>(aQ, scsh+64, rowstart, csr_src, csr_f, W21, aR);
  k_stats<16,false><<<128,256,0,stream>>>(aR, nullptr, stats+128, NN);
  k_fin<<<1,32,0,stream>>>(stats+128, g21, b21, scsh+128, nullptr, (float)NN, 16);
  // layer 3: 16 -> 16
  k_conv<16,16,true><<<2048,256,0,stream>>>(aR, scsh+128, rowstart, csr_src, csr_f, W3, aP);
  k_stats<16,false><<<128,256,0,stream>>>(aP, nullptr, stats+192, NN);
  k_fin<<<1,32,0,stream>>>(stats+192, g3, b3, scsh+192, nullptr, (float)NN, 16);
  // layer 4: 16 -> 16
  k_conv<16,16,true><<<2048,256,0,stream>>>(aP, scsh+192, rowstart, csr_src, csr_f, W4, aQ);
  k_stats<16,false><<<128,256,0,stream>>>(aQ, nullptr, stats+256, NN);
  k_fin<<<1,32,0,stream>>>(stats+256, g4, b4, scsh+256, nullptr, (float)NN, 16);
  // combine bn4(a4)+bn21(a21) -> aP, then layer 5: 16 -> 32
  k_comb<<<1024,256,0,stream>>>(aQ, aR, scsh+256, scsh+128, aP);
  k_conv<16,32,false><<<2048,256,0,stream>>>(aP, nullptr, rowstart, csr_src, csr_f, W5, a5);
  k_stats<32,false><<<128,256,0,stream>>>(a5, nullptr, stats+320, NN);
  k_fin<<<1,32,0,stream>>>(stats+320, g5, b5, scsh+320, nullptr, (float)NN, 32);

  // pooling: wave-per-cell gather (atomic-free max/sum)
  k_poolg<<<(SS+3)/4,256,0,stream>>>(cellstart, order, pos, a5, scsh+320, xpf, pp, cntf, tw);

  // pair graph
  k_pair_deg<<<512,256,0,stream>>>(slotb, pp, deg2, mxp);
  k_scan1<<<31,256,0,stream>>>(deg2, rowstart2, bsum2, SS);
  k_scan2<<<1,1024,0,stream>>>(bsum2, 31);
  k_scan3<<<31,256,0,stream>>>(rowstart2, bsum2, SS);
  k_pair_fill<<<512,256,0,stream>>>(slotb, rowstart2, cursor2, pairsrc);

  // pool conv 6: 32 -> 32 (input xp, already bn5-folded)
  k_pconv<<<SS,64,0,stream>>>(xpf, nullptr, rowstart2, pairsrc, pp, (const float*)mxp, W6, a6);
  k_stats<32,true><<<128,256,0,stream>>>(a6, cntf, stats+384, SS);
  k_fin<<<1,32,0,stream>>>(stats+384, g6, b6, scsh+384, tw, 0.f, 32);
  // pool conv 7: 32 -> 32
  k_pconv<<<SS,64,0,stream>>>(a6, scsh+384, rowstart2, pairsrc, pp, (const float*)mxp, W7, a7);
  k_stats<32,true><<<128,256,0,stream>>>(a7, cntf, stats+448, SS);
  k_fin<<<1,32,0,stream>>>(stats+448, g7, b7, scsh+448, tw, 0.f, 32);

  // global mean + fc
  k_final<<<16,64,0,stream>>>(a7, scsh+448, cntf, fcW, outp);
}